// Round 1
// baseline (1224.273 us; speedup 1.0000x reference)
//
#include <hip/hip_runtime.h>

#define IN_DIM 128
#define HID 64

__device__ __forceinline__ float relu(float v) { return v > 0.f ? v : 0.f; }

// ---- degree count: deg[col[e]] += 1 ----
__global__ __launch_bounds__(256) void k_deg(const int* __restrict__ col,
                                             float* __restrict__ deg, int E) {
    int e = blockIdx.x * 256 + threadIdx.x;
    if (e < E) atomicAdd(&deg[col[e]], 1.0f);
}

// ---- dinv = deg>0 ? rsqrt(deg) : 0 (in place) ----
__global__ __launch_bounds__(256) void k_dinv(float* __restrict__ deg, int N) {
    int n = blockIdx.x * 256 + threadIdx.x;
    if (n < N) {
        float d = deg[n];
        deg[n] = d > 0.f ? rsqrtf(d) : 0.f;
    }
}

// ---- norm[e] = dinv[row[e]] * dinv[col[e]] ----
__global__ __launch_bounds__(256) void k_norm(const int* __restrict__ row,
                                              const int* __restrict__ col,
                                              const float* __restrict__ dinv,
                                              float* __restrict__ nrm, int E) {
    int e = blockIdx.x * 256 + threadIdx.x;
    if (e < E) nrm[e] = dinv[row[e]] * dinv[col[e]];
}

// ---- dual GEMM layer 1: X[N,128] -> O1=relu(X@W1+B1)[N,64], O2=X@W2[N,64] ----
// wave handles 16 nodes; lane = output feature j. x loads are wave-uniform
// broadcast float4; weight loads coalesced 256B/wave (L1-resident, 32KB each).
__global__ __launch_bounds__(256) void k_gemm1(const float* __restrict__ X,
                                               const float* __restrict__ W1,
                                               const float* __restrict__ W2,
                                               const float* __restrict__ B1,
                                               float* __restrict__ O1,
                                               float* __restrict__ O2, int N) {
    const int lane = threadIdx.x & 63;
    const int wv = threadIdx.x >> 6;
    const int node0 = blockIdx.x * 64 + wv * 16;
    if (node0 >= N) return;
    const int nv = (node0 + 16 <= N) ? 16 : (N - node0);
    float acc1[16], acc2[16];
#pragma unroll
    for (int i = 0; i < 16; i++) { acc1[i] = 0.f; acc2[i] = 0.f; }

    for (int k = 0; k < IN_DIM; k += 4) {
        const float w1a = W1[(k + 0) * 64 + lane];
        const float w1b = W1[(k + 1) * 64 + lane];
        const float w1c = W1[(k + 2) * 64 + lane];
        const float w1d = W1[(k + 3) * 64 + lane];
        const float w2a = W2[(k + 0) * 64 + lane];
        const float w2b = W2[(k + 1) * 64 + lane];
        const float w2c = W2[(k + 2) * 64 + lane];
        const float w2d = W2[(k + 3) * 64 + lane];
        if (nv == 16) {
#pragma unroll
            for (int i = 0; i < 16; i++) {
                const float4 xv = *(const float4*)(X + (size_t)(node0 + i) * IN_DIM + k);
                acc1[i] += xv.x * w1a + xv.y * w1b + xv.z * w1c + xv.w * w1d;
                acc2[i] += xv.x * w2a + xv.y * w2b + xv.z * w2c + xv.w * w2d;
            }
        } else {
            for (int i = 0; i < nv; i++) {
                const float4 xv = *(const float4*)(X + (size_t)(node0 + i) * IN_DIM + k);
                acc1[i] += xv.x * w1a + xv.y * w1b + xv.z * w1c + xv.w * w1d;
                acc2[i] += xv.x * w2a + xv.y * w2b + xv.z * w2c + xv.w * w2d;
            }
        }
    }
    const float b = B1[lane];
    for (int i = 0; i < nv; i++) {
        const size_t o = (size_t)(node0 + i) * 64 + lane;
        O1[o] = relu(acc1[i] + b);
        O2[o] = acc2[i];
    }
}

// ---- dual GEMM layer 2: input x3 = [X1 | relu(AGG+CB)] (virtual concat) ----
__global__ __launch_bounds__(256) void k_gemm2(const float* __restrict__ X1,
                                               const float* __restrict__ AGG,
                                               const float* __restrict__ CB,
                                               const float* __restrict__ W1,
                                               const float* __restrict__ W2,
                                               const float* __restrict__ B1,
                                               float* __restrict__ O1,
                                               float* __restrict__ O2, int N) {
    const int lane = threadIdx.x & 63;
    const int wv = threadIdx.x >> 6;
    const int node0 = blockIdx.x * 64 + wv * 16;
    if (node0 >= N) return;
    const int nv = (node0 + 16 <= N) ? 16 : (N - node0);
    float acc1[16], acc2[16];
#pragma unroll
    for (int i = 0; i < 16; i++) { acc1[i] = 0.f; acc2[i] = 0.f; }

    for (int k = 0; k < 2 * HID; k += 4) {
        const float w1a = W1[(k + 0) * 64 + lane];
        const float w1b = W1[(k + 1) * 64 + lane];
        const float w1c = W1[(k + 2) * 64 + lane];
        const float w1d = W1[(k + 3) * 64 + lane];
        const float w2a = W2[(k + 0) * 64 + lane];
        const float w2b = W2[(k + 1) * 64 + lane];
        const float w2c = W2[(k + 2) * 64 + lane];
        const float w2d = W2[(k + 3) * 64 + lane];
        if (k < HID) {
            for (int i = 0; i < nv; i++) {
                const float4 xv = *(const float4*)(X1 + (size_t)(node0 + i) * 64 + k);
                acc1[i] += xv.x * w1a + xv.y * w1b + xv.z * w1c + xv.w * w1d;
                acc2[i] += xv.x * w2a + xv.y * w2b + xv.z * w2c + xv.w * w2d;
            }
        } else {
            const float4 cb = *(const float4*)(CB + (k - HID));
            for (int i = 0; i < nv; i++) {
                float4 xv = *(const float4*)(AGG + (size_t)(node0 + i) * 64 + (k - HID));
                xv.x = relu(xv.x + cb.x);
                xv.y = relu(xv.y + cb.y);
                xv.z = relu(xv.z + cb.z);
                xv.w = relu(xv.w + cb.w);
                acc1[i] += xv.x * w1a + xv.y * w1b + xv.z * w1c + xv.w * w1d;
                acc2[i] += xv.x * w2a + xv.y * w2b + xv.z * w2c + xv.w * w2d;
            }
        }
    }
    const float b = B1[lane];
    for (int i = 0; i < nv; i++) {
        const size_t o = (size_t)(node0 + i) * 64 + lane;
        O1[o] = relu(acc1[i] + b);
        O2[o] = acc2[i];
    }
}

// ---- edge scatter: agg[col[e]][f] += H[row[e]][f] * norm[e]; one wave/edge ----
__global__ __launch_bounds__(256) void k_scatter(const int* __restrict__ row,
                                                 const int* __restrict__ col,
                                                 const float* __restrict__ nrm,
                                                 const float* __restrict__ H,
                                                 float* __restrict__ AGG, int E) {
    const int e = blockIdx.x * 4 + (threadIdx.x >> 6);
    if (e >= E) return;
    const int lane = threadIdx.x & 63;
    const int r = row[e];
    const int c = col[e];
    const float w = nrm[e];
    const float v = H[(size_t)r * 64 + lane] * w;
    atomicAdd(&AGG[(size_t)c * 64 + lane], v);
}

// ---- combine: x7 = x5 + relu(agg2+cb2); out = x7@fc2w + fc2b + c3b; h3 = x7@c3w ----
__global__ __launch_bounds__(256) void k_combine(const float* __restrict__ X5,
                                                 const float* __restrict__ AGG2,
                                                 const float* __restrict__ CB2,
                                                 const float* __restrict__ FC2W,
                                                 const float* __restrict__ FC2B,
                                                 const float* __restrict__ C3W,
                                                 const float* __restrict__ C3B,
                                                 float* __restrict__ X7,
                                                 float* __restrict__ H3,
                                                 float* __restrict__ OUT, int N) {
    const int lane = threadIdx.x & 63;
    const int wv = threadIdx.x >> 6;
    const int n = blockIdx.x * 4 + wv;
    if (n >= N) return;
    const size_t o = (size_t)n * 64 + lane;
    const float v = X5[o] + relu(AGG2[o] + CB2[lane]);
    X7[o] = v;
    float p9 = v * FC2W[lane];
    float p10 = v * C3W[lane];
#pragma unroll
    for (int s = 32; s >= 1; s >>= 1) {
        p9 += __shfl_xor(p9, s, 64);
        p10 += __shfl_xor(p10, s, 64);
    }
    if (lane == 0) {
        OUT[n] = p9 + FC2B[0] + C3B[0];
        H3[n] = p10;
    }
}

// ---- final scatter: out[col[e]] += h3[row[e]] * norm[e] ----
__global__ __launch_bounds__(256) void k_scatter3(const int* __restrict__ row,
                                                  const int* __restrict__ col,
                                                  const float* __restrict__ nrm,
                                                  const float* __restrict__ H3,
                                                  float* __restrict__ OUT, int E) {
    int e = blockIdx.x * 256 + threadIdx.x;
    if (e < E) atomicAdd(&OUT[col[e]], H3[row[e]] * nrm[e]);
}

extern "C" void kernel_launch(void* const* d_in, const int* in_sizes, int n_in,
                              void* d_out, int out_size, void* d_ws, size_t ws_size,
                              hipStream_t stream) {
    const float* x    = (const float*)d_in[0];
    const float* fcw  = (const float*)d_in[1];
    const float* fcb  = (const float*)d_in[2];
    const float* c1w  = (const float*)d_in[3];
    const float* c1b  = (const float*)d_in[4];
    const float* f1w  = (const float*)d_in[5];
    const float* f1b  = (const float*)d_in[6];
    const float* c2w  = (const float*)d_in[7];
    const float* c2b  = (const float*)d_in[8];
    const float* f2w  = (const float*)d_in[9];
    const float* f2b  = (const float*)d_in[10];
    const float* c3w  = (const float*)d_in[11];
    const float* c3b  = (const float*)d_in[12];
    const int*   ei   = (const int*)d_in[13];

    const int N = in_sizes[0] / IN_DIM;
    const int E = in_sizes[13] / 2;
    const int* row = ei;
    const int* col = ei + E;
    float* out = (float*)d_out;

    // workspace layout (floats), with aliasing: agg2<-h1, x7<-x1, h3<-agg1
    float* ws = (float*)d_ws;
    const size_t Npad = ((size_t)N + 127) & ~(size_t)127;
    const size_t Epad = ((size_t)E + 127) & ~(size_t)127;
    const size_t NF = (size_t)N * 64;
    float* deg  = ws;            // N (becomes dinv in place)
    float* nrm  = deg + Npad;    // E
    float* x1   = nrm + Epad;    // N*64
    float* h1   = x1 + NF;       // N*64
    float* agg1 = h1 + NF;       // N*64
    float* x5   = agg1 + NF;     // N*64
    float* h2   = x5 + NF;       // N*64
    float* agg2 = h1;            // reuse (h1 dead after scatter1)
    float* x7   = x1;            // reuse (x1 dead after gemm2)
    float* h3   = agg1;          // reuse (agg1 dead after gemm2)

    const int gE   = (E + 255) / 256;
    const int gN   = (N + 255) / 256;
    const int gG   = (N + 63) / 64;
    const int gS   = (E + 3) / 4;
    const int gC   = (N + 3) / 4;

    hipMemsetAsync(deg, 0, (size_t)N * sizeof(float), stream);
    k_deg<<<gE, 256, 0, stream>>>(col, deg, E);
    k_dinv<<<gN, 256, 0, stream>>>(deg, N);
    k_norm<<<gE, 256, 0, stream>>>(row, col, deg, nrm, E);

    k_gemm1<<<gG, 256, 0, stream>>>(x, fcw, c1w, fcb, x1, h1, N);
    hipMemsetAsync(agg1, 0, NF * sizeof(float), stream);
    k_scatter<<<gS, 256, 0, stream>>>(row, col, nrm, h1, agg1, E);

    k_gemm2<<<gG, 256, 0, stream>>>(x1, agg1, c1b, f1w, c2w, f1b, x5, h2, N);
    hipMemsetAsync(agg2, 0, NF * sizeof(float), stream);  // stream-ordered: after scatter1 read h1
    k_scatter<<<gS, 256, 0, stream>>>(row, col, nrm, h2, agg2, E);

    k_combine<<<gC, 256, 0, stream>>>(x5, agg2, c2b, f2w, f2b, c3w, c3b, x7, h3, out, N);
    k_scatter3<<<gE, 256, 0, stream>>>(row, col, nrm, h3, out, E);
}